// Round 3
// baseline (2483.374 us; speedup 1.0000x reference)
//
#include <hip/hip_runtime.h>

// Problem constants (B=64, T=512, D=256, Q=8, K=1024)
#define NTOK   32768
#define DDIM   256
#define KCODES 1024
#define QLAYERS 8

#define MT     64     // tokens per block
#define NCHUNK 32     // codes staged per chunk
#define NCH    (KCODES / NCHUNK)
#define DELTA  1e-4f  // re-rank margin (>> mfma-vs-fp32 err ~2e-7, >> np-vs-fp32 ~3e-5)

typedef __attribute__((ext_vector_type(8))) short bf16x8;
typedef __attribute__((ext_vector_type(4))) float f32x4;

// d_out layout: [0, N*D) residual->output | [N*D] loss | [N*D+1, +Q*N) indices (as float)
// d_ws  layout: emb_hi [Q*K*D bf16] | emb_lo [Q*K*D bf16] | ce [Q*K f32]

__device__ __forceinline__ unsigned short bf16_rne(float x) {
  unsigned u = __float_as_uint(x);
  return (unsigned short)((u + 0x7fffu + ((u >> 16) & 1u)) >> 16);
}

__device__ __forceinline__ void split8(float4 a, float4 b, bf16x8* hi, bf16x8* lo) {
  float xs[8] = {a.x, a.y, a.z, a.w, b.x, b.y, b.z, b.w};
  bf16x8 h, l;
#pragma unroll
  for (int j = 0; j < 8; ++j) {
    unsigned short hs = bf16_rne(xs[j]);
    float hf = __uint_as_float(((unsigned)hs) << 16);
    float lf = xs[j] - hf;                       // exact
    h[j] = (short)hs;
    l[j] = (short)bf16_rne(lf);
  }
  *hi = h; *lo = l;
}

__global__ void ce_kernel(const float* __restrict__ emb, float* __restrict__ ce) {
  int gid  = blockIdx.x * blockDim.x + threadIdx.x;
  int code = gid >> 6;
  int lane = threadIdx.x & 63;
  float4 v = reinterpret_cast<const float4*>(emb + (size_t)code * DDIM)[lane];
  float s = v.x * v.x + v.y * v.y + v.z * v.z + v.w * v.w;
#pragma unroll
  for (int off = 32; off; off >>= 1) s += __shfl_xor(s, off);
  if (lane == 0) ce[code] = s;
}

// bf16 hi/lo split with 16B-group XOR swizzle baked into the global copy
__global__ void split_kernel(const float* __restrict__ emb,
                             short* __restrict__ hi, short* __restrict__ lo) {
  int g  = blockIdx.x * blockDim.x + threadIdx.x;
  int c  = g >> 5;
  int dg = g & 31;
  const float4* p = reinterpret_cast<const float4*>(emb + (size_t)c * DDIM + dg * 8);
  float4 a = p[0], b = p[1];
  bf16x8 h, l;
  split8(a, b, &h, &l);
  size_t o = (size_t)c * DDIM + (size_t)((dg ^ (c & 7)) * 8);
  *reinterpret_cast<bf16x8*>(hi + o) = h;
  *reinterpret_cast<bf16x8*>(lo + o) = l;
}

__global__ void init_kernel(const float* __restrict__ x, float* __restrict__ out) {
  size_t i = (size_t)blockIdx.x * blockDim.x + threadIdx.x;
  reinterpret_cast<float4*>(out)[i] = reinterpret_cast<const float4*>(x)[i];
  if (i == 0) out[(size_t)NTOK * DDIM] = 0.0f;
}

__global__ __launch_bounds__(256, 2)
void vq_mfma_kernel(const short* __restrict__ ehi, const short* __restrict__ elo,
                    const float* __restrict__ emb, const float* __restrict__ ce,
                    float* __restrict__ res, float* __restrict__ idx_out,
                    float* __restrict__ loss_accum) {
  __shared__ __align__(16) short bs[2][2][NCHUNK * DDIM];  // 64 KB
  __shared__ __align__(16) float ce_s[KCODES];             // 4 KB
  __shared__ __align__(16) float res_row[DDIM];            // 1 KB (re-rank)
  __shared__ float cf_s[MT];
  __shared__ float redv[2][MT];
  __shared__ float red2[2][MT];
  __shared__ int   redi[2][MT];
  __shared__ int   idx_s[MT];
  __shared__ int   flag_s[MT];
  __shared__ float rr_v[256];
  __shared__ int   rr_i[256];
  __shared__ float wsum[4];

  const int t    = threadIdx.x;
  const int lane = t & 63, w = t >> 6;
  const int wr   = w >> 1, wc = w & 1;
  const int l15  = lane & 15, lq = lane >> 4;
  const int tok0 = blockIdx.x * MT;

  reinterpret_cast<float4*>(ce_s)[t] = reinterpret_cast<const float4*>(ce)[t];

  // ---- phase 1: cf = ||residual||^2 per token (EXACT r1 arithmetic) ----
  {
    const int m = t >> 2, p = t & 3;
    const float4* r4 =
        reinterpret_cast<const float4*>(res + (size_t)(tok0 + m) * DDIM + p * 64);
    float s = 0.f;
#pragma unroll
    for (int j = 0; j < 16; ++j) {
      float4 v = r4[j];
      s = fmaf(v.x, v.x, s); s = fmaf(v.y, v.y, s);
      s = fmaf(v.z, v.z, s); s = fmaf(v.w, v.w, s);
    }
    s += __shfl_xor(s, 1);
    s += __shfl_xor(s, 2);
    if (p == 0) cf_s[m] = s;
  }

  // ---- A load + hi/lo split into registers ----
  bf16x8 ahi[2][8], alo[2][8];
#pragma unroll
  for (int mi = 0; mi < 2; ++mi) {
    const int tok = tok0 + wr * 32 + mi * 16 + l15;
#pragma unroll
    for (int ds = 0; ds < 8; ++ds) {
      const float4* p =
          reinterpret_cast<const float4*>(res + (size_t)tok * DDIM + ds * 32 + lq * 8);
      split8(p[0], p[1], &ahi[mi][ds], &alo[mi][ds]);
    }
  }

  auto stage = [&](int buf, int kc) {
    const size_t base = (size_t)kc * NCHUNK * DDIM;
#pragma unroll
    for (int i = 0; i < 4; ++i) {
      const int eo  = i * 2048 + t * 8;
      const int lo_ = i * 2048 + w * 512;
      __builtin_amdgcn_global_load_lds(
          (const __attribute__((address_space(1))) unsigned int*)(ehi + base + eo),
          (__attribute__((address_space(3))) unsigned int*)&bs[buf][0][lo_], 16, 0, 0);
      __builtin_amdgcn_global_load_lds(
          (const __attribute__((address_space(1))) unsigned int*)(elo + base + eo),
          (__attribute__((address_space(3))) unsigned int*)&bs[buf][1][lo_], 16, 0, 0);
    }
  };

  stage(0, 0);
  __syncthreads();

  float cfreg[2][4];
#pragma unroll
  for (int mi = 0; mi < 2; ++mi)
#pragma unroll
    for (int r = 0; r < 4; ++r) cfreg[mi][r] = cf_s[wr * 32 + mi * 16 + lq * 4 + r];

  float minv[2][4], min2[2][4]; int mini[2][4];
#pragma unroll
  for (int mi = 0; mi < 2; ++mi)
#pragma unroll
    for (int r = 0; r < 4; ++r) {
      minv[mi][r] = 3.4e38f; min2[mi][r] = 3.4e38f; mini[mi][r] = 0;
    }

  const int crow = wc * 16 + l15;
  const int eswz = (crow & 7) << 3;

  for (int kc = 0; kc < NCH; ++kc) {
    const int buf = kc & 1;
    if (kc + 1 < NCH) stage(buf ^ 1, kc + 1);

    f32x4 acc0 = {0.f, 0.f, 0.f, 0.f};
    f32x4 acc1 = {0.f, 0.f, 0.f, 0.f};
    const short* bh = bs[buf][0];
    const short* bl = bs[buf][1];
#pragma unroll
    for (int ds = 0; ds < 8; ++ds) {
      const int e = crow * DDIM + ((ds * 32 + lq * 8) ^ eswz);
      bf16x8 bhv = *reinterpret_cast<const bf16x8*>(&bh[e]);
      bf16x8 blv = *reinterpret_cast<const bf16x8*>(&bl[e]);
      acc0 = __builtin_amdgcn_mfma_f32_16x16x32_bf16(ahi[0][ds], bhv, acc0, 0, 0, 0);
      acc1 = __builtin_amdgcn_mfma_f32_16x16x32_bf16(ahi[1][ds], bhv, acc1, 0, 0, 0);
      acc0 = __builtin_amdgcn_mfma_f32_16x16x32_bf16(alo[0][ds], bhv, acc0, 0, 0, 0);
      acc1 = __builtin_amdgcn_mfma_f32_16x16x32_bf16(alo[1][ds], bhv, acc1, 0, 0, 0);
      acc0 = __builtin_amdgcn_mfma_f32_16x16x32_bf16(ahi[0][ds], blv, acc0, 0, 0, 0);
      acc1 = __builtin_amdgcn_mfma_f32_16x16x32_bf16(ahi[1][ds], blv, acc1, 0, 0, 0);
    }

    const int   cg  = kc * NCHUNK + crow;
    const float cev = ce_s[cg];
#pragma unroll
    for (int r = 0; r < 4; ++r) {
      float d0v = (cfreg[0][r] + cev) - 2.0f * acc0[r];
      if (d0v < minv[0][r]) { min2[0][r] = minv[0][r]; minv[0][r] = d0v; mini[0][r] = cg; }
      else if (d0v < min2[0][r]) min2[0][r] = d0v;
      float d1v = (cfreg[1][r] + cev) - 2.0f * acc1[r];
      if (d1v < minv[1][r]) { min2[1][r] = minv[1][r]; minv[1][r] = d1v; mini[1][r] = cg; }
      else if (d1v < min2[1][r]) min2[1][r] = d1v;
    }
    __syncthreads();
  }

  // ---- cross-lane top-2 argmin reduce within 16-lane groups ----
#pragma unroll
  for (int mi = 0; mi < 2; ++mi)
#pragma unroll
    for (int r = 0; r < 4; ++r) {
      float v = minv[mi][r], v2s = min2[mi][r]; int ix = mini[mi][r];
#pragma unroll
      for (int off = 1; off <= 8; off <<= 1) {
        float ov = __shfl_xor(v, off);
        float o2 = __shfl_xor(v2s, off);
        int   oi = __shfl_xor(ix, off);
        if (ov < v || (ov == v && oi < ix)) { v2s = fminf(v, o2); v = ov; ix = oi; }
        else v2s = fminf(v2s, ov);
      }
      if (l15 == 0) {
        int tw = wr * 32 + mi * 16 + lq * 4 + r;
        redv[wc][tw] = v; red2[wc][tw] = v2s; redi[wc][tw] = ix;
      }
    }
  __syncthreads();
  if (t < MT) {
    float v0 = redv[0][t], s0 = red2[0][t]; int i0 = redi[0][t];
    float v1 = redv[1][t], s1 = red2[1][t]; int i1 = redi[1][t];
    float bv, b2; int bi;
    if (v1 < v0 || (v1 == v0 && i1 < i0)) { bv = v1; bi = i1; b2 = fminf(v0, s1); }
    else { bv = v0; bi = i0; b2 = fminf(v1, s0); }
    idx_s[t]  = bi;
    flag_s[t] = (b2 - bv < DELTA) ? 1 : 0;
  }
  __syncthreads();

  // ---- re-rank flagged tokens with EXACT r1 fp32 arithmetic ----
  for (int f = 0; f < MT; ++f) {
    if (!flag_s[f]) continue;
    if (t < 64) {
      float4 v = *reinterpret_cast<const float4*>(res + (size_t)(tok0 + f) * DDIM + t * 4);
      *reinterpret_cast<float4*>(&res_row[t * 4]) = v;
    }
    __syncthreads();
    const float cf = cf_s[f];
    float bestv = 3.4e38f; int besti = 0;
#pragma unroll
    for (int u = 0; u < 4; ++u) {
      int c = t * 4 + u;
      const float4* e4 = reinterpret_cast<const float4*>(emb + (size_t)c * DDIM);
      float acc = 0.f;
#pragma unroll 8
      for (int j = 0; j < 64; ++j) {
        float4 b = e4[j];
        float4 a = *reinterpret_cast<const float4*>(&res_row[j * 4]);
        acc = fmaf(a.x, b.x, acc); acc = fmaf(a.y, b.y, acc);
        acc = fmaf(a.z, b.z, acc); acc = fmaf(a.w, b.w, acc);
      }
      float t1 = cf + ce_s[c];
      float dist = t1 - 2.0f * acc;
      if (dist < bestv) { bestv = dist; besti = c; }   // ascending c: strict <
    }
    rr_v[t] = bestv; rr_i[t] = besti;
    __syncthreads();
    if (t < 64) {
      float v = rr_v[t]; int ix = rr_i[t];
#pragma unroll
      for (int s = 64; s < 256; s += 64) {
        float ov = rr_v[t + s]; int oi = rr_i[t + s];
        if (ov < v || (ov == v && oi < ix)) { v = ov; ix = oi; }
      }
#pragma unroll
      for (int off = 1; off < 64; off <<= 1) {
        float ov = __shfl_xor(v, off); int oi = __shfl_xor(ix, off);
        if (ov < v || (ov == v && oi < ix)) { v = ov; ix = oi; }
      }
      if (t == 0) idx_s[f] = ix;
    }
    __syncthreads();
  }

  if (t < MT) idx_out[tok0 + t] = (float)idx_s[t];

  // ---- phase 4: residual -= emb[idx]; loss += 1.25*mean(new_res^2) ----
  {
    const int m = t >> 2, p = t & 3;
    const int ci = idx_s[m];
    const float4* e4 =
        reinterpret_cast<const float4*>(emb + (size_t)ci * DDIM + p * 64);
    float4* r4 = reinterpret_cast<float4*>(res + (size_t)(tok0 + m) * DDIM + p * 64);
    float s = 0.f;
#pragma unroll
    for (int j = 0; j < 16; ++j) {
      float4 r = r4[j], e = e4[j];
      float4 nr = make_float4(r.x - e.x, r.y - e.y, r.z - e.z, r.w - e.w);
      s = fmaf(nr.x, nr.x, s); s = fmaf(nr.y, nr.y, s);
      s = fmaf(nr.z, nr.z, s); s = fmaf(nr.w, nr.w, s);
      r4[j] = nr;
    }
#pragma unroll
    for (int off = 32; off; off >>= 1) s += __shfl_xor(s, off);
    if ((t & 63) == 0) wsum[t >> 6] = s;
  }
  __syncthreads();
  if (t == 0) {
    float total = wsum[0] + wsum[1] + wsum[2] + wsum[3];
    atomicAdd(loss_accum, total * (1.25f / ((float)NTOK * (float)DDIM)));
  }
}

__global__ void final_kernel(const float* __restrict__ x, float* __restrict__ out) {
  size_t i = (size_t)blockIdx.x * blockDim.x + threadIdx.x;
  float4 xv = reinterpret_cast<const float4*>(x)[i];
  float4 r  = reinterpret_cast<float4*>(out)[i];
  reinterpret_cast<float4*>(out)[i] =
      make_float4(xv.x - r.x, xv.y - r.y, xv.z - r.z, xv.w - r.w);
}

extern "C" void kernel_launch(void* const* d_in, const int* in_sizes, int n_in,
                              void* d_out, int out_size, void* d_ws, size_t ws_size,
                              hipStream_t stream) {
  const float* x   = (const float*)d_in[0];
  const float* emb = (const float*)d_in[1];
  float* out      = (float*)d_out;
  float* loss     = out + (size_t)NTOK * DDIM;
  float* idx_base = loss + 1;

  short* ehi = (short*)d_ws;
  short* elo = ehi + (size_t)QLAYERS * KCODES * DDIM;
  float* ce  = (float*)(elo + (size_t)QLAYERS * KCODES * DDIM);

  split_kernel<<<QLAYERS * KCODES * 32 / 256, 256, 0, stream>>>(emb, ehi, elo);
  ce_kernel<<<QLAYERS * KCODES * 64 / 256, 256, 0, stream>>>(emb, ce);
  init_kernel<<<NTOK * DDIM / 4 / 256, 256, 0, stream>>>(x, out);
  for (int q = 0; q < QLAYERS; ++q) {
    vq_mfma_kernel<<<NTOK / MT, 256, 0, stream>>>(
        ehi + (size_t)q * KCODES * DDIM, elo + (size_t)q * KCODES * DDIM,
        emb + (size_t)q * KCODES * DDIM, ce + (size_t)q * KCODES, out,
        idx_base + (size_t)q * NTOK, loss);
  }
  final_kernel<<<NTOK * DDIM / 4 / 256, 256, 0, stream>>>(x, out);
}

// Round 5
// 1722.750 us; speedup vs baseline: 1.4415x; 1.4415x over previous
//
#include <hip/hip_runtime.h>

// Problem constants (B=64, T=512, D=256, Q=8, K=1024)
#define NTOK   32768
#define DDIM   256
#define KCODES 1024
#define QLAYERS 8

#define MT     64               // tokens per block
#define NCHUNK 64               // codes staged per chunk
#define NCH    (KCODES / NCHUNK)
#define DELTA  4e-4f            // cert margin >> 2*E_f16 + np-vs-fp32 slack
#define RPAD   260              // padded res row (float)

typedef __attribute__((ext_vector_type(8))) _Float16 f16x8;
typedef __attribute__((ext_vector_type(4))) float f32x4;

// d_out: [0,N*D) output | [N*D] loss | [N*D+1,+Q*N) indices (as float)
// d_ws : eh16 [Q*K*D f16, x256-scaled, swizzled] | ce [Q*K f32] | loss_part [512 f32]

__global__ void ce_kernel(const float* __restrict__ emb, float* __restrict__ ce) {
  int gid  = blockIdx.x * blockDim.x + threadIdx.x;
  int code = gid >> 6;
  int lane = threadIdx.x & 63;
  float4 v = reinterpret_cast<const float4*>(emb + (size_t)code * DDIM)[lane];
  float s = v.x * v.x + v.y * v.y + v.z * v.z + v.w * v.w;
#pragma unroll
  for (int off = 32; off; off >>= 1) s += __shfl_xor(s, off);
  if (lane == 0) ce[code] = s;
}

// f16 conversion of codebooks, scaled by 256, 16B-group XOR swizzle baked in
__global__ void split16_kernel(const float* __restrict__ emb, _Float16* __restrict__ eh) {
  int g  = blockIdx.x * blockDim.x + threadIdx.x;   // Q*K*32
  int c  = g >> 5;
  int dg = g & 31;
  const float4* p = reinterpret_cast<const float4*>(emb + (size_t)c * DDIM + dg * 8);
  float4 a = p[0], b = p[1];
  f16x8 h;
  h[0] = (_Float16)(a.x * 256.f); h[1] = (_Float16)(a.y * 256.f);
  h[2] = (_Float16)(a.z * 256.f); h[3] = (_Float16)(a.w * 256.f);
  h[4] = (_Float16)(b.x * 256.f); h[5] = (_Float16)(b.y * 256.f);
  h[6] = (_Float16)(b.z * 256.f); h[7] = (_Float16)(b.w * 256.f);
  *reinterpret_cast<f16x8*>(eh + (size_t)c * DDIM + (size_t)((dg ^ (c & 7)) * 8)) = h;
}

__device__ __forceinline__ void lexins(float d, int c, float v[3], int ci[3]) {
  bool l2 = (d < v[2]) || (d == v[2] && c < ci[2]);
  bool l1 = (d < v[1]) || (d == v[1] && c < ci[1]);
  bool l0 = (d < v[0]) || (d == v[0] && c < ci[0]);
  v[2] = l1 ? v[1] : (l2 ? d : v[2]);  ci[2] = l1 ? ci[1] : (l2 ? c : ci[2]);
  v[1] = l0 ? v[0] : (l1 ? d : v[1]);  ci[1] = l0 ? ci[0] : (l1 ? c : ci[1]);
  v[0] = l0 ? d : v[0];                ci[0] = l0 ? c : ci[0];
}

// value-only insert (codes visited in ascending index per lane -> strict <)
__device__ __forceinline__ void ins3(float d, int c, float v[3], int ci[3]) {
  bool l2 = d < v[2];
  bool l1 = d < v[1];
  bool l0 = d < v[0];
  v[2] = l1 ? v[1] : (l2 ? d : v[2]);  ci[2] = l1 ? ci[1] : (l2 ? c : ci[2]);
  v[1] = l0 ? v[0] : (l1 ? d : v[1]);  ci[1] = l0 ? ci[0] : (l1 ? c : ci[1]);
  v[0] = l0 ? d : v[0];                ci[0] = l0 ? c : ci[0];
}

// EXACT np-matching distance (r1/r3-proven): sequential fmaf chain d=0..255
__device__ __forceinline__ float exact_dist(const float* __restrict__ rrow,
                                            const float* __restrict__ erow,
                                            float cf, float cev) {
  float acc = 0.f;
  const float4* e4 = reinterpret_cast<const float4*>(erow);
  const float4* a4 = reinterpret_cast<const float4*>(rrow);
#pragma unroll 8
  for (int j = 0; j < 64; ++j) {
    float4 b = e4[j], a = a4[j];
    acc = fmaf(a.x, b.x, acc); acc = fmaf(a.y, b.y, acc);
    acc = fmaf(a.z, b.z, acc); acc = fmaf(a.w, b.w, acc);
  }
  float t1 = cf + cev;
  return t1 - 2.0f * acc;
}

__global__ __launch_bounds__(256, 1)
void vq_fused_kernel(const float* __restrict__ x, const float* __restrict__ emb,
                     const _Float16* __restrict__ eh16, const float* __restrict__ ce,
                     float* __restrict__ out, float* __restrict__ idx_out,
                     float* __restrict__ loss_part) {
  __shared__ __align__(16) float res_s[MT][RPAD];                 // 66560 B
  __shared__ __align__(16) _Float16 estage[2][NCHUNK * DDIM];     // 65536 B
  __shared__ __align__(16) float ce_s[KCODES];                    // 4096 B
  __shared__ float cf_s[MT];
  __shared__ float t3v[2][MT][3];
  __shared__ int   t3i[2][MT][3];
  __shared__ int   idx_s[MT];
  __shared__ unsigned long long fullmask;
  __shared__ float wsum[4];

  float* rr_v = &t3v[0][0][0];   // aliased scratch for full re-rank (t3 consumed)
  int*   rr_i = &t3i[0][0][0];

  const int t    = threadIdx.x;
  const int lane = t & 63, w = t >> 6;
  const int wr   = w >> 1, wc = w & 1;
  const int l15  = lane & 15, lq = lane >> 4;
  const int tok0 = blockIdx.x * MT;

  // ---- load x tile -> res_s ----
#pragma unroll
  for (int j = 0; j < 16; ++j) {
    int u = j * 256 + t;
    float4 xv = reinterpret_cast<const float4*>(x)[(size_t)blockIdx.x * 4096 + u];
    *reinterpret_cast<float4*>(&res_s[u >> 6][(u & 63) * 4]) = xv;
  }

  float lossacc = 0.f;
  const int crow0 = wc * 32 + l15;        // chunk-local code rows
  const int crow1 = crow0 + 16;
  const int esw   = (crow0 & 7) * 8;      // same for crow1

  for (int q = 0; q < QLAYERS; ++q) {
    const float*    embq = emb + (size_t)q * KCODES * DDIM;
    const _Float16* ehq  = eh16 + (size_t)q * KCODES * DDIM;
    const float*    ceq  = ce + (size_t)q * KCODES;

    __syncthreads();   // B0: res_s ready; all prior-layer LDS reads done

    // issue chunk-0 staging loads early (land under cf/A-split work)
    uint4 sreg[8];
#pragma unroll
    for (int i = 0; i < 8; ++i)
      sreg[i] = *reinterpret_cast<const uint4*>(ehq + i * 2048 + t * 8);

    // stage ce for the layer
    reinterpret_cast<float4*>(ce_s)[t] = reinterpret_cast<const float4*>(ceq)[t];

    // ---- cf = ||res||^2 (EXACT r1 arithmetic) ----
    {
      const int m = t >> 2, p = t & 3;
      float s = 0.f;
#pragma unroll
      for (int j = 0; j < 16; ++j) {
        float4 v = *reinterpret_cast<const float4*>(&res_s[m][p * 64 + j * 4]);
        s = fmaf(v.x, v.x, s); s = fmaf(v.y, v.y, s);
        s = fmaf(v.z, v.z, s); s = fmaf(v.w, v.w, s);
      }
      s += __shfl_xor(s, 1);
      s += __shfl_xor(s, 2);
      if (p == 0) cf_s[m] = s;
    }

    // ---- A-split: res -> f16 frags in registers ----
    f16x8 af[2][8];
#pragma unroll
    for (int mi = 0; mi < 2; ++mi) {
      const int tok = wr * 32 + mi * 16 + l15;
#pragma unroll
      for (int ds = 0; ds < 8; ++ds) {
        const float* pr = &res_s[tok][ds * 32 + lq * 8];
        float4 a = *reinterpret_cast<const float4*>(pr);
        float4 b = *reinterpret_cast<const float4*>(pr + 4);
        f16x8 h;
        h[0] = (_Float16)a.x; h[1] = (_Float16)a.y; h[2] = (_Float16)a.z; h[3] = (_Float16)a.w;
        h[4] = (_Float16)b.x; h[5] = (_Float16)b.y; h[6] = (_Float16)b.z; h[7] = (_Float16)b.w;
        af[mi][ds] = h;
      }
    }

    __syncthreads();   // B1: cf_s/ce_s ready; prev estage reads long done
#pragma unroll
    for (int i = 0; i < 8; ++i)
      *reinterpret_cast<uint4*>(&estage[0][i * 2048 + t * 8]) = sreg[i];
    __syncthreads();   // B1b: chunk 0 visible

    float cfreg[2][4];
#pragma unroll
    for (int mi = 0; mi < 2; ++mi)
#pragma unroll
      for (int r = 0; r < 4; ++r) cfreg[mi][r] = cf_s[wr * 32 + mi * 16 + lq * 4 + r];

    float tv[8][3]; int ti[8][3];
#pragma unroll
    for (int s = 0; s < 8; ++s)
#pragma unroll
      for (int k = 0; k < 3; ++k) { tv[s][k] = 3.4e38f; ti[s][k] = 0; }

    // ---- K-loop: reg-staged double buffer ----
    for (int kc = 0; kc < NCH; ++kc) {
      const int buf = kc & 1;
      if (kc + 1 < NCH) {   // issue next-chunk loads; latency hides under MFMA
        const _Float16* src = ehq + (size_t)(kc + 1) * NCHUNK * DDIM;
#pragma unroll
        for (int i = 0; i < 8; ++i)
          sreg[i] = *reinterpret_cast<const uint4*>(src + i * 2048 + t * 8);
      }

      f32x4 acc[2][2];
#pragma unroll
      for (int mi = 0; mi < 2; ++mi)
#pragma unroll
        for (int c2 = 0; c2 < 2; ++c2) acc[mi][c2] = (f32x4){0.f, 0.f, 0.f, 0.f};

      const _Float16* bb = estage[buf];
#pragma unroll
      for (int ds = 0; ds < 8; ++ds) {
        const int eo = (ds * 32 + lq * 8) ^ esw;
        f16x8 b0 = *reinterpret_cast<const f16x8*>(&bb[crow0 * DDIM + eo]);
        f16x8 b1 = *reinterpret_cast<const f16x8*>(&bb[crow1 * DDIM + eo]);
        acc[0][0] = __builtin_amdgcn_mfma_f32_16x16x32_f16(af[0][ds], b0, acc[0][0], 0, 0, 0);
        acc[1][0] = __builtin_amdgcn_mfma_f32_16x16x32_f16(af[1][ds], b0, acc[1][0], 0, 0, 0);
        acc[0][1] = __builtin_amdgcn_mfma_f32_16x16x32_f16(af[0][ds], b1, acc[0][1], 0, 0, 0);
        acc[1][1] = __builtin_amdgcn_mfma_f32_16x16x32_f16(af[1][ds], b1, acc[1][1], 0, 0, 0);
      }

      const int   cg0 = kc * NCHUNK + crow0, cg1 = kc * NCHUNK + crow1;
      const float ce0 = ce_s[cg0], ce1 = ce_s[cg1];
#pragma unroll
      for (int mi = 0; mi < 2; ++mi)
#pragma unroll
        for (int r = 0; r < 4; ++r) {
          // acc = dot*256; dist = fl(t1 - acc/128), single rounding like np
          float d0 = fmaf(-0.0078125f, acc[mi][0][r], cfreg[mi][r] + ce0);
          ins3(d0, cg0, tv[mi * 4 + r], ti[mi * 4 + r]);
          float d1 = fmaf(-0.0078125f, acc[mi][1][r], cfreg[mi][r] + ce1);
          ins3(d1, cg1, tv[mi * 4 + r], ti[mi * 4 + r]);
        }

      __syncthreads();   // B2a: all waves done reading estage[buf^1] (prev) & [buf]
      if (kc + 1 < NCH) {
#pragma unroll
        for (int i = 0; i < 8; ++i)
          *reinterpret_cast<uint4*>(&estage[buf ^ 1][i * 2048 + t * 8]) = sreg[i];
      }
      __syncthreads();   // B2b: next chunk visible
    }

    // ---- merge top-3 across 16-lane groups (lex: value, then lower index) ----
#pragma unroll
    for (int s = 0; s < 8; ++s) {
#pragma unroll
      for (int off = 1; off <= 8; off <<= 1) {
        float a0 = __shfl_xor(tv[s][0], off), a1 = __shfl_xor(tv[s][1], off),
              a2 = __shfl_xor(tv[s][2], off);
        int   b0 = __shfl_xor(ti[s][0], off), b1 = __shfl_xor(ti[s][1], off),
              b2 = __shfl_xor(ti[s][2], off);
        lexins(a0, b0, tv[s], ti[s]);
        lexins(a1, b1, tv[s], ti[s]);
        lexins(a2, b2, tv[s], ti[s]);
      }
      if (l15 == 0) {
        const int mi = s >> 2, r = s & 3;
        const int tok = wr * 32 + mi * 16 + lq * 4 + r;
        t3v[wc][tok][0] = tv[s][0]; t3v[wc][tok][1] = tv[s][1]; t3v[wc][tok][2] = tv[s][2];
        t3i[wc][tok][0] = ti[s][0]; t3i[wc][tok][1] = ti[s][1]; t3i[wc][tok][2] = ti[s][2];
      }
    }
    __syncthreads();

    // ---- classify + cheap exact re-rank (wave 0; deterministic ballot) ----
    if (t < MT) {
      float v[3]; int ci[3];
      v[0] = t3v[0][t][0]; v[1] = t3v[0][t][1]; v[2] = t3v[0][t][2];
      ci[0] = t3i[0][t][0]; ci[1] = t3i[0][t][1]; ci[2] = t3i[0][t][2];
      lexins(t3v[1][t][0], t3i[1][t][0], v, ci);
      lexins(t3v[1][t][1], t3i[1][t][1], v, ci);
      lexins(t3v[1][t][2], t3i[1][t][2], v, ci);
      int best = ci[0];
      bool needfull = false;
      if (v[1] - v[0] >= DELTA) {
        // certified unique
      } else if (v[2] - v[0] >= DELTA) {   // exactly {ci0, ci1} candidates
        int ia = min(ci[0], ci[1]), ib = max(ci[0], ci[1]);
        float da = exact_dist(&res_s[t][0], embq + (size_t)ia * DDIM, cf_s[t], ce_s[ia]);
        float db = exact_dist(&res_s[t][0], embq + (size_t)ib * DDIM, cf_s[t], ce_s[ib]);
        best = (db < da) ? ib : ia;        // tie -> lower index
      } else {
        needfull = true;
      }
      idx_s[t] = best;
      unsigned long long bm = __ballot(needfull);
      if (t == 0) fullmask = bm;
    }
    __syncthreads();

    // ---- full exact re-rank for rare ambiguous tokens ----
    unsigned long long fm = fullmask;
    while (fm) {
      const int f = __builtin_ctzll(fm);
      fm &= fm - 1;
      const float cfv = cf_s[f];
      float bestv = 3.4e38f; int besti = 0;
#pragma unroll
      for (int u = 0; u < 4; ++u) {
        int c = t * 4 + u;
        const float4* e4 = reinterpret_cast<const float4*>(embq + (size_t)c * DDIM);
        float acc = 0.f;
#pragma unroll 8
        for (int j = 0; j < 64; ++j) {
          float4 b = e4[j];
          float4 a = *reinterpret_cast<const float4*>(&res_s[f][j * 4]);
          acc = fmaf(a.x, b.x, acc); acc = fmaf(a.y, b.y, acc);
          acc = fmaf(a.z, b.z, acc); acc = fmaf(a.w, b.w, acc);
        }
        float dist = (cfv + ce_s[c]) - 2.0f * acc;
        if (dist < bestv) { bestv = dist; besti = c; }
      }
      rr_v[t] = bestv; rr_i[t] = besti;
      __syncthreads();
      if (t < 64) {
        float vb = rr_v[t]; int ib = rr_i[t];
#pragma unroll
        for (int s = 64; s < 256; s += 64) {
          float ov = rr_v[t + s]; int oi = rr_i[t + s];
          if (ov < vb || (ov == vb && oi < ib)) { vb = ov; ib = oi; }
        }
#pragma unroll
        for (int off = 1; off < 64; off <<= 1) {
          float ov = __shfl_xor(vb, off); int oi = __shfl_xor(ib, off);
          if (ov < vb || (ov == vb && oi < ib)) { vb = ov; ib = oi; }
        }
        if (t == 0) idx_s[f] = ib;
      }
      __syncthreads();
    }

    if (t < MT) idx_out[(size_t)q * NTOK + tok0 + t] = (float)idx_s[t];

    // ---- residual update in LDS + loss partial ----
    {
      const int m = t >> 2, p = t & 3;
      const int ci = idx_s[m];
      const float4* e4 = reinterpret_cast<const float4*>(embq + (size_t)ci * DDIM + p * 64);
      float s = 0.f;
#pragma unroll
      for (int j = 0; j < 16; ++j) {
        float4 e = e4[j];
        float4* rp = reinterpret_cast<float4*>(&res_s[m][p * 64 + j * 4]);
        float4 r = *rp;
        float4 nr = make_float4(r.x - e.x, r.y - e.y, r.z - e.z, r.w - e.w);
        s = fmaf(nr.x, nr.x, s); s = fmaf(nr.y, nr.y, s);
        s = fmaf(nr.z, nr.z, s); s = fmaf(nr.w, nr.w, s);
        *rp = nr;
      }
#pragma unroll
      for (int off = 32; off; off >>= 1) s += __shfl_xor(s, off);
      if ((t & 63) == 0) wsum[w] = s;
    }
    __syncthreads();
    if (t == 0) lossacc += wsum[0] + wsum[1] + wsum[2] + wsum[3];
  }

  __syncthreads();
  // ---- out = x - res ----
#pragma unroll
  for (int j = 0; j < 16; ++j) {
    int u = j * 256 + t;
    float4 xv = reinterpret_cast<const float4*>(x)[(size_t)blockIdx.x * 4096 + u];
    float4 r = *reinterpret_cast<const float4*>(&res_s[u >> 6][(u & 63) * 4]);
    reinterpret_cast<float4*>(out)[(size_t)blockIdx.x * 4096 + u] =
        make_float4(xv.x - r.x, xv.y - r.y, xv.z - r.z, xv.w - r.w);
  }
  if (t == 0) loss_part[blockIdx.x] = lossacc;
}

__global__ void loss_final_kernel(const float* __restrict__ part, float* __restrict__ loss_out) {
  int t = threadIdx.x;   // 64 threads
  float s = 0.f;
#pragma unroll
  for (int j = 0; j < 8; ++j) s += part[j * 64 + t];
#pragma unroll
  for (int off = 32; off; off >>= 1) s += __shfl_xor(s, off);
  if (t == 0) *loss_out = s * (1.25f / ((float)NTOK * (float)DDIM));
}

extern "C" void kernel_launch(void* const* d_in, const int* in_sizes, int n_in,
                              void* d_out, int out_size, void* d_ws, size_t ws_size,
                              hipStream_t stream) {
  const float* x   = (const float*)d_in[0];
  const float* emb = (const float*)d_in[1];
  float* out      = (float*)d_out;
  float* loss     = out + (size_t)NTOK * DDIM;
  float* idx_base = loss + 1;

  _Float16* eh16    = (_Float16*)d_ws;                                   // 4 MB
  float* ce         = (float*)(eh16 + (size_t)QLAYERS * KCODES * DDIM);  // 32 KB
  float* loss_part  = ce + (size_t)QLAYERS * KCODES;                     // 2 KB

  split16_kernel<<<QLAYERS * KCODES * 32 / 256, 256, 0, stream>>>(emb, eh16);
  ce_kernel<<<QLAYERS * KCODES * 64 / 256, 256, 0, stream>>>(emb, ce);
  vq_fused_kernel<<<NTOK / MT, 256, 0, stream>>>(x, emb, eh16, ce, out, idx_base, loss_part);
  loss_final_kernel<<<1, 64, 0, stream>>>(loss_part, loss);
}

// Round 6
// 1277.945 us; speedup vs baseline: 1.9433x; 1.3481x over previous
//
#include <hip/hip_runtime.h>

// Problem constants (B=64, T=512, D=256, Q=8, K=1024)
#define NTOK   32768
#define DDIM   256
#define KCODES 1024
#define QLAYERS 8

#define MT     64               // tokens per block
#define NCHUNK 32               // codes staged per chunk
#define NCH    (KCODES / NCHUNK)
#define DELTA  4e-4f            // cert margin >> 2*E_f16 worst-case + np-vs-fp32 slack
#define RPAD   260              // padded res row (float)

typedef __attribute__((ext_vector_type(8))) _Float16 f16x8;
typedef __attribute__((ext_vector_type(4))) float f32x4;

// d_out: [0,N*D) output | [N*D] loss | [N*D+1,+Q*N) indices (as float)
// d_ws : eh16 [Q*K*D f16, x256-scaled, swizzled] | ce [Q*K f32] | loss_part [512 f32]

__global__ void ce_kernel(const float* __restrict__ emb, float* __restrict__ ce) {
  int gid  = blockIdx.x * blockDim.x + threadIdx.x;
  int code = gid >> 6;
  int lane = threadIdx.x & 63;
  float4 v = reinterpret_cast<const float4*>(emb + (size_t)code * DDIM)[lane];
  float s = v.x * v.x + v.y * v.y + v.z * v.z + v.w * v.w;
#pragma unroll
  for (int off = 32; off; off >>= 1) s += __shfl_xor(s, off);
  if (lane == 0) ce[code] = s;
}

// f16 conversion of codebooks, scaled by 256, 16B-group XOR swizzle baked in
__global__ void split16_kernel(const float* __restrict__ emb, _Float16* __restrict__ eh) {
  int g  = blockIdx.x * blockDim.x + threadIdx.x;   // Q*K*32
  int c  = g >> 5;
  int dg = g & 31;
  const float4* p = reinterpret_cast<const float4*>(emb + (size_t)c * DDIM + dg * 8);
  float4 a = p[0], b = p[1];
  f16x8 h;
  h[0] = (_Float16)(a.x * 256.f); h[1] = (_Float16)(a.y * 256.f);
  h[2] = (_Float16)(a.z * 256.f); h[3] = (_Float16)(a.w * 256.f);
  h[4] = (_Float16)(b.x * 256.f); h[5] = (_Float16)(b.y * 256.f);
  h[6] = (_Float16)(b.z * 256.f); h[7] = (_Float16)(b.w * 256.f);
  *reinterpret_cast<f16x8*>(eh + (size_t)c * DDIM + (size_t)((dg ^ (c & 7)) * 8)) = h;
}

__device__ __forceinline__ void lexins(float d, int c, float v[3], int ci[3]) {
  bool l2 = (d < v[2]) || (d == v[2] && c < ci[2]);
  bool l1 = (d < v[1]) || (d == v[1] && c < ci[1]);
  bool l0 = (d < v[0]) || (d == v[0] && c < ci[0]);
  v[2] = l1 ? v[1] : (l2 ? d : v[2]);  ci[2] = l1 ? ci[1] : (l2 ? c : ci[2]);
  v[1] = l0 ? v[0] : (l1 ? d : v[1]);  ci[1] = l0 ? ci[0] : (l1 ? c : ci[1]);
  v[0] = l0 ? d : v[0];                ci[0] = l0 ? c : ci[0];
}

// value-only insert (codes visited in ascending index per lane -> strict <)
__device__ __forceinline__ void ins3(float d, int c, float v[3], int ci[3]) {
  bool l2 = d < v[2];
  bool l1 = d < v[1];
  bool l0 = d < v[0];
  v[2] = l1 ? v[1] : (l2 ? d : v[2]);  ci[2] = l1 ? ci[1] : (l2 ? c : ci[2]);
  v[1] = l0 ? v[0] : (l1 ? d : v[1]);  ci[1] = l0 ? ci[0] : (l1 ? c : ci[1]);
  v[0] = l0 ? d : v[0];                ci[0] = l0 ? c : ci[0];
}

// EXACT np-matching distance (r1/r3-proven): sequential fmaf chain d=0..255
__device__ __forceinline__ float exact_dist(const float* __restrict__ rrow,
                                            const float* __restrict__ erow,
                                            float cf, float cev) {
  float acc = 0.f;
  const float4* e4 = reinterpret_cast<const float4*>(erow);
  const float4* a4 = reinterpret_cast<const float4*>(rrow);
#pragma unroll 8
  for (int j = 0; j < 64; ++j) {
    float4 b = e4[j], a = a4[j];
    acc = fmaf(a.x, b.x, acc); acc = fmaf(a.y, b.y, acc);
    acc = fmaf(a.z, b.z, acc); acc = fmaf(a.w, b.w, acc);
  }
  float t1 = cf + cev;
  return t1 - 2.0f * acc;
}

__global__ __launch_bounds__(256, 1)
void vq_fused_kernel(const float* __restrict__ x, const float* __restrict__ emb,
                     const _Float16* __restrict__ eh16, const float* __restrict__ ce,
                     float* __restrict__ out, float* __restrict__ idx_out,
                     float* __restrict__ loss_part) {
  __shared__ __align__(16) float res_s[MT][RPAD];                 // 66560 B
  __shared__ __align__(16) _Float16 estage[2][NCHUNK * DDIM];     // 32768 B
  __shared__ __align__(16) float ce_s[KCODES];                    // 4096 B
  __shared__ float cf_s[MT];
  __shared__ float t3v[MT][3];
  __shared__ int   t3i[MT][3];
  __shared__ int   idx_s[MT];
  __shared__ float rr_v[256];
  __shared__ int   rr_i[256];
  __shared__ unsigned long long fullmask;
  __shared__ float wsum[4];

  const int t    = threadIdx.x;
  const int lane = t & 63, w = t >> 6;
  const int l15  = lane & 15, lq = lane >> 4;
  const int tok0 = blockIdx.x * MT;

  // ---- load x tile -> res_s ----
#pragma unroll
  for (int j = 0; j < 16; ++j) {
    int u = j * 256 + t;
    float4 xv = reinterpret_cast<const float4*>(x)[(size_t)blockIdx.x * 4096 + u];
    *reinterpret_cast<float4*>(&res_s[u >> 6][(u & 63) * 4]) = xv;
  }

  float lossacc = 0.f;

  for (int q = 0; q < QLAYERS; ++q) {
    const float*    embq = emb + (size_t)q * KCODES * DDIM;
    const _Float16* ehq  = eh16 + (size_t)q * KCODES * DDIM;
    const float*    ceq  = ce + (size_t)q * KCODES;

    __syncthreads();   // B0: res_s ready; all prior-layer LDS reads done

    // issue chunk-0 staging loads early (land under cf/A-split work)
    uint4 sreg[4];
#pragma unroll
    for (int i = 0; i < 4; ++i)
      sreg[i] = *reinterpret_cast<const uint4*>(ehq + i * 2048 + t * 8);

    // stage ce for the layer
    reinterpret_cast<float4*>(ce_s)[t] = reinterpret_cast<const float4*>(ceq)[t];

    // ---- cf = ||res||^2 (EXACT r1 arithmetic) ----
    {
      const int m = t >> 2, p = t & 3;
      float s = 0.f;
#pragma unroll
      for (int j = 0; j < 16; ++j) {
        float4 v = *reinterpret_cast<const float4*>(&res_s[m][p * 64 + j * 4]);
        s = fmaf(v.x, v.x, s); s = fmaf(v.y, v.y, s);
        s = fmaf(v.z, v.z, s); s = fmaf(v.w, v.w, s);
      }
      s += __shfl_xor(s, 1);
      s += __shfl_xor(s, 2);
      if (p == 0) cf_s[m] = s;
    }

    // ---- A-split: wave w owns tokens [w*16, w*16+16) ----
    f16x8 af[8];
#pragma unroll
    for (int ds = 0; ds < 8; ++ds) {
      const float* pr = &res_s[w * 16 + l15][ds * 32 + lq * 8];
      float4 a = *reinterpret_cast<const float4*>(pr);
      float4 b = *reinterpret_cast<const float4*>(pr + 4);
      f16x8 h;
      h[0] = (_Float16)a.x; h[1] = (_Float16)a.y; h[2] = (_Float16)a.z; h[3] = (_Float16)a.w;
      h[4] = (_Float16)b.x; h[5] = (_Float16)b.y; h[6] = (_Float16)b.z; h[7] = (_Float16)b.w;
      af[ds] = h;
    }

    __syncthreads();   // B1: cf_s/ce_s ready; prev-layer estage reads done
#pragma unroll
    for (int i = 0; i < 4; ++i)
      *reinterpret_cast<uint4*>(&estage[0][i * 2048 + t * 8]) = sreg[i];
    __syncthreads();   // B1b: chunk 0 visible

    float cfreg[4];
#pragma unroll
    for (int r = 0; r < 4; ++r) cfreg[r] = cf_s[w * 16 + lq * 4 + r];

    float tv[4][3]; int ti[4][3];
#pragma unroll
    for (int s = 0; s < 4; ++s)
#pragma unroll
      for (int k = 0; k < 3; ++k) { tv[s][k] = 3.4e38f; ti[s][k] = 0; }

    // ---- K-loop: 32 chunks of 32 codes; wave covers ALL chunk codes ----
    for (int kc = 0; kc < NCH; ++kc) {
      const int buf = kc & 1;
      if (kc + 1 < NCH) {   // issue next-chunk loads; latency hides under MFMA
        const _Float16* src = ehq + (size_t)(kc + 1) * NCHUNK * DDIM;
#pragma unroll
        for (int i = 0; i < 4; ++i)
          sreg[i] = *reinterpret_cast<const uint4*>(src + i * 2048 + t * 8);
      }

      f32x4 acc[2][2];   // [code-frag][ds-parity] -> 4 independent MFMA chains
#pragma unroll
      for (int c2 = 0; c2 < 2; ++c2)
#pragma unroll
        for (int pp = 0; pp < 2; ++pp) acc[c2][pp] = (f32x4){0.f, 0.f, 0.f, 0.f};

      const _Float16* bb = estage[buf];
#pragma unroll
      for (int ds = 0; ds < 8; ++ds) {
        const int col = ds * 32 + lq * 8;
        const int r0  = l15;               // code rows of this chunk
        const int r1  = 16 + l15;
        f16x8 b0 = *reinterpret_cast<const f16x8*>(&bb[r0 * DDIM + (col ^ ((r0 & 7) * 8))]);
        f16x8 b1 = *reinterpret_cast<const f16x8*>(&bb[r1 * DDIM + (col ^ ((r1 & 7) * 8))]);
        acc[0][ds & 1] = __builtin_amdgcn_mfma_f32_16x16x32_f16(af[ds], b0, acc[0][ds & 1], 0, 0, 0);
        acc[1][ds & 1] = __builtin_amdgcn_mfma_f32_16x16x32_f16(af[ds], b1, acc[1][ds & 1], 0, 0, 0);
      }

#pragma unroll
      for (int c2 = 0; c2 < 2; ++c2) {
        const int   cg  = kc * NCHUNK + c2 * 16 + l15;
        const float cev = ce_s[cg];
#pragma unroll
        for (int r = 0; r < 4; ++r) {
          float dot = acc[c2][0][r] + acc[c2][1][r];   // dot*256
          float d   = fmaf(-0.0078125f, dot, cfreg[r] + cev);
          ins3(d, cg, tv[r], ti[r]);
        }
      }

      __syncthreads();   // B2a: all waves done reading estage[buf^1] (prev)
      if (kc + 1 < NCH) {
#pragma unroll
        for (int i = 0; i < 4; ++i)
          *reinterpret_cast<uint4*>(&estage[buf ^ 1][i * 2048 + t * 8]) = sreg[i];
      }
      __syncthreads();   // B2b: next chunk visible
    }

    // ---- merge top-3 across the 16-lane code group (token fully in-wave) ----
#pragma unroll
    for (int s = 0; s < 4; ++s) {
#pragma unroll
      for (int off = 1; off <= 8; off <<= 1) {
        float a0 = __shfl_xor(tv[s][0], off), a1 = __shfl_xor(tv[s][1], off),
              a2 = __shfl_xor(tv[s][2], off);
        int   b0 = __shfl_xor(ti[s][0], off), b1 = __shfl_xor(ti[s][1], off),
              b2 = __shfl_xor(ti[s][2], off);
        lexins(a0, b0, tv[s], ti[s]);
        lexins(a1, b1, tv[s], ti[s]);
        lexins(a2, b2, tv[s], ti[s]);
      }
      if (l15 == 0) {
        const int tok = w * 16 + lq * 4 + s;
        t3v[tok][0] = tv[s][0]; t3v[tok][1] = tv[s][1]; t3v[tok][2] = tv[s][2];
        t3i[tok][0] = ti[s][0]; t3i[tok][1] = ti[s][1]; t3i[tok][2] = ti[s][2];
      }
    }
    __syncthreads();

    // ---- classify + cheap exact re-rank (wave 0; deterministic ballot) ----
    if (t < MT) {
      float v0 = t3v[t][0], v1 = t3v[t][1], v2 = t3v[t][2];
      int   c0 = t3i[t][0], c1 = t3i[t][1];
      int best = c0;
      bool needfull = false;
      if (v1 - v0 >= DELTA) {
        // certified unique
      } else if (v2 - v0 >= DELTA) {   // exactly {c0, c1} candidates
        int ia = min(c0, c1), ib = max(c0, c1);
        float da = exact_dist(&res_s[t][0], embq + (size_t)ia * DDIM, cf_s[t], ce_s[ia]);
        float db = exact_dist(&res_s[t][0], embq + (size_t)ib * DDIM, cf_s[t], ce_s[ib]);
        best = (db < da) ? ib : ia;    // tie -> lower index
      } else {
        needfull = true;
      }
      idx_s[t] = best;
      unsigned long long bm = __ballot(needfull);
      if (t == 0) fullmask = bm;
    }
    __syncthreads();

    // ---- full exact re-rank for rare ambiguous tokens ----
    unsigned long long fm = fullmask;
    while (fm) {
      const int f = __builtin_ctzll(fm);
      fm &= fm - 1;
      const float cfv = cf_s[f];
      float bestv = 3.4e38f; int besti = 0;
#pragma unroll
      for (int u = 0; u < 4; ++u) {
        int c = t * 4 + u;
        const float4* e4 = reinterpret_cast<const float4*>(embq + (size_t)c * DDIM);
        float acc = 0.f;
#pragma unroll 8
        for (int j = 0; j < 64; ++j) {
          float4 b = e4[j];
          float4 a = *reinterpret_cast<const float4*>(&res_s[f][j * 4]);
          acc = fmaf(a.x, b.x, acc); acc = fmaf(a.y, b.y, acc);
          acc = fmaf(a.z, b.z, acc); acc = fmaf(a.w, b.w, acc);
        }
        float dist = (cfv + ce_s[c]) - 2.0f * acc;
        if (dist < bestv) { bestv = dist; besti = c; }
      }
      rr_v[t] = bestv; rr_i[t] = besti;
      __syncthreads();
      if (t < 64) {
        float vb = rr_v[t]; int ib = rr_i[t];
#pragma unroll
        for (int s = 64; s < 256; s += 64) {
          float ov = rr_v[t + s]; int oi = rr_i[t + s];
          if (ov < vb || (ov == vb && oi < ib)) { vb = ov; ib = oi; }
        }
#pragma unroll
        for (int off = 1; off < 64; off <<= 1) {
          float ov = __shfl_xor(vb, off); int oi = __shfl_xor(ib, off);
          if (ov < vb || (ov == vb && oi < ib)) { vb = ov; ib = oi; }
        }
        if (t == 0) idx_s[f] = ib;
      }
      __syncthreads();
    }

    if (t < MT) idx_out[(size_t)q * NTOK + tok0 + t] = (float)idx_s[t];

    // ---- residual update in LDS + loss partial ----
    {
      const int m = t >> 2, p = t & 3;
      const int ci = idx_s[m];
      const float4* e4 = reinterpret_cast<const float4*>(embq + (size_t)ci * DDIM + p * 64);
      float s = 0.f;
#pragma unroll
      for (int j = 0; j < 16; ++j) {
        float4 e = e4[j];
        float4* rp = reinterpret_cast<float4*>(&res_s[m][p * 64 + j * 4]);
        float4 r = *rp;
        float4 nr = make_float4(r.x - e.x, r.y - e.y, r.z - e.z, r.w - e.w);
        s = fmaf(nr.x, nr.x, s); s = fmaf(nr.y, nr.y, s);
        s = fmaf(nr.z, nr.z, s); s = fmaf(nr.w, nr.w, s);
        *rp = nr;
      }
#pragma unroll
      for (int off = 32; off; off >>= 1) s += __shfl_xor(s, off);
      if ((t & 63) == 0) wsum[w] = s;
    }
    __syncthreads();
    if (t == 0) lossacc += wsum[0] + wsum[1] + wsum[2] + wsum[3];
  }

  __syncthreads();
  // ---- out = x - res ----
#pragma unroll
  for (int j = 0; j < 16; ++j) {
    int u = j * 256 + t;
    float4 xv = reinterpret_cast<const float4*>(x)[(size_t)blockIdx.x * 4096 + u];
    float4 r = *reinterpret_cast<const float4*>(&res_s[u >> 6][(u & 63) * 4]);
    reinterpret_cast<float4*>(out)[(size_t)blockIdx.x * 4096 + u] =
        make_float4(xv.x - r.x, xv.y - r.y, xv.z - r.z, xv.w - r.w);
  }
  if (t == 0) loss_part[blockIdx.x] = lossacc;
}

__global__ void loss_final_kernel(const float* __restrict__ part, float* __restrict__ loss_out) {
  int t = threadIdx.x;   // 64 threads
  float s = 0.f;
#pragma unroll
  for (int j = 0; j < 8; ++j) s += part[j * 64 + t];
#pragma unroll
  for (int off = 32; off; off >>= 1) s += __shfl_xor(s, off);
  if (t == 0) *loss_out = s * (1.25f / ((float)NTOK * (float)DDIM));
}

extern "C" void kernel_launch(void* const* d_in, const int* in_sizes, int n_in,
                              void* d_out, int out_size, void* d_ws, size_t ws_size,
                              hipStream_t stream) {
  const float* x   = (const float*)d_in[0];
  const float* emb = (const float*)d_in[1];
  float* out      = (float*)d_out;
  float* loss     = out + (size_t)NTOK * DDIM;
  float* idx_base = loss + 1;

  _Float16* eh16    = (_Float16*)d_ws;                                   // 4 MB
  float* ce         = (float*)(eh16 + (size_t)QLAYERS * KCODES * DDIM);  // 32 KB
  float* loss_part  = ce + (size_t)QLAYERS * KCODES;                     // 2 KB

  split16_kernel<<<QLAYERS * KCODES * 32 / 256, 256, 0, stream>>>(emb, eh16);
  ce_kernel<<<QLAYERS * KCODES * 64 / 256, 256, 0, stream>>>(emb, ce);
  vq_fused_kernel<<<NTOK / MT, 256, 0, stream>>>(x, emb, eh16, ce, out, idx_base, loss_part);
  loss_final_kernel<<<1, 64, 0, stream>>>(loss_part, loss);
}